// Round 8
// baseline (253.404 us; speedup 1.0000x reference)
//
#include <hip/hip_runtime.h>
#include <math.h>

#define B_ 4
#define C_ 200
#define CH_ 100          // rows per batch half; block r-pair = (c0, c0+100)
#define W_ 300
#define WP_ 304
#define H_ 128
#define NH_ 8
#define PH_ 16
#define FF_ 512
#define L_ 2
#define MAXLEN_ 200
#define PEN_ 512
#define WVS_ 136         // LDS B-matrix row stride (bf16)
#define NTILE_ 19        // ceil(W/16)

typedef __bf16 bf16x8 __attribute__((ext_vector_type(8)));
typedef __bf16 bf16x2 __attribute__((ext_vector_type(2)));
typedef float f32x4v __attribute__((ext_vector_type(4)));

// prep grid — R27: layouts for coalesced mega GEMVs.
// vb natural [li][b][w][h] (no vT scatter), WrT transposed bf16,
// W1b/W2b plain bf16 converts (no transposes needed anymore).
#define SEG_PEW   64                          // 512 pos / 8
#define SEG_KV    (SEG_PEW + 200)             // 4 b * 2 layers * 25 tiles(12 words)
#define SEG_WRT   (SEG_KV + 32)               // Wr transpose: 2 layers * 16 (32x32 tiles)
#define SEG_CONV  (SEG_WRT + 128)             // W1b/W2b converts: 262144 elems
#define PREP_BLOCKS SEG_CONV                  // 424

__global__ __launch_bounds__(128) void prep_kernel(
        const float* __restrict__ Wf, const float* __restrict__ bfv,
        const float* __restrict__ words,
        const float* __restrict__ Wk, const float* __restrict__ bk,
        const float* __restrict__ Wv, const float* __restrict__ bv,
        const float* __restrict__ Wr, const float* __restrict__ W1,
        const float* __restrict__ W2,
        __bf16* __restrict__ kb, __bf16* __restrict__ PEWb, __bf16* __restrict__ vb,
        __bf16* __restrict__ WrT, __bf16* __restrict__ W1b, __bf16* __restrict__ W2b) {
    __shared__ __align__(16) float s_buf[12 * H_];   // PEW: 8x128 pe | KV: 12x128 words
    __shared__ float s_tile[32][33];
    int t = threadIdx.x;
    if (blockIdx.x < SEG_PEW) {
        // ---- PEW: 8 positions/block; pe rows in LDS (broadcast), 32 acc/thread.
        int p0 = blockIdx.x * 8;
        {
            int j = (t < 64) ? t : (t - 64);
            double f = exp(-(double)j * (log(10000.0) / 63.0));
            #pragma unroll
            for (int r = 0; r < 8; ++r) {
                double a = (double)(p0 + r) * f;
                s_buf[r * H_ + t] = (float)((t < 64) ? sin(a) : cos(a));
            }
        }
        __syncthreads();
        float acc0[8], acc1[8], acc2[8], acc3[8];
        #pragma unroll
        for (int r = 0; r < 8; ++r) { acc0[r] = 0.f; acc1[r] = 0.f; acc2[r] = 0.f; acc3[r] = 0.f; }
        #pragma unroll 2
        for (int j = 0; j < H_; ++j) {
            float w0 = Wf[0 * H_ * H_ + j * H_ + t];
            float w1 = Wf[1 * H_ * H_ + j * H_ + t];
            float w2 = Wf[2 * H_ * H_ + j * H_ + t];
            float w3 = Wf[3 * H_ * H_ + j * H_ + t];
            #pragma unroll
            for (int r = 0; r < 8; ++r) {
                float pv = s_buf[r * H_ + j];   // LDS broadcast
                acc0[r] += pv * w0;
                acc1[r] += pv * w1;
                acc2[r] += pv * w2;
                acc3[r] += pv * w3;
            }
        }
        float bfr = bfv[t];
        #pragma unroll
        for (int r = 0; r < 8; ++r) {
            int p = p0 + r;
            PEWb[(0 * PEN_ + p) * H_ + t] = (__bf16)(acc0[r] + bfr);
            PEWb[(1 * PEN_ + p) * H_ + t] = (__bf16)acc1[r];
            PEWb[(2 * PEN_ + p) * H_ + t] = (__bf16)acc2[r];
            PEWb[(3 * PEN_ + p) * H_ + t] = (__bf16)acc3[r];
        }
    } else if (blockIdx.x < SEG_KV) {
        // ---- KV: 12 words/block, one layer/block, LDS-broadcast x; k AND v
        // both written in natural coalesced [w][h] layout.
        int idx = blockIdx.x - SEG_PEW;
        int bb = idx / 50;
        int rem = idx % 50;
        int li = rem / 25;
        int w0 = (rem % 25) * 12;
        for (int i = t; i < 12 * H_; i += 128) {
            int r = i >> 7, j = i & 127;
            s_buf[i] = words[((size_t)(bb * W_ + w0 + r)) * H_ + j];
        }
        __syncthreads();
        const float* wk = Wk + li * H_ * H_;
        const float* wv = Wv + li * H_ * H_;
        float ak[12], av[12];
        #pragma unroll
        for (int r = 0; r < 12; ++r) { ak[r] = 0.f; av[r] = 0.f; }
        #pragma unroll 2
        for (int j = 0; j < H_; ++j) {
            float kw = wk[j * H_ + t];
            float vw = wv[j * H_ + t];
            #pragma unroll
            for (int r = 0; r < 12; ++r) {
                float x = s_buf[r * H_ + j];    // LDS broadcast
                ak[r] += x * kw;
                av[r] += x * vw;
            }
        }
        float bkv = bk[li * H_ + t], bvv = bv[li * H_ + t];
        #pragma unroll
        for (int r = 0; r < 12; ++r) {
            size_t row = (size_t)(li * B_ * W_ + bb * W_ + w0 + r) * H_ + t;
            kb[row] = (__bf16)(ak[r] + bkv);
            vb[row] = (__bf16)(av[r] + bvv);
        }
    } else if (blockIdx.x < SEG_WRT) {
        // ---- WrT: transpose Wr (f32 -> bf16), 32x32 LDS tiles.
        int q = blockIdx.x - SEG_KV;
        int li = q >> 4;
        int tile = q & 15;
        int tr = tile >> 2, tc = tile & 3;
        int i2 = t >> 5, j2 = t & 31;
        #pragma unroll
        for (int k = 0; k < 8; ++k) {
            int row = tr * 32 + i2 + 4 * k;
            s_tile[i2 + 4 * k][j2] = Wr[((size_t)(li * H_ + row)) * H_ + tc * 32 + j2];
        }
        __syncthreads();
        #pragma unroll
        for (int k = 0; k < 8; ++k) {
            int o2 = i2 + 4 * k;
            WrT[((size_t)(li * H_ + tc * 32 + o2)) * H_ + tr * 32 + j2] =
                (__bf16)s_tile[j2][o2];
        }
    } else {
        // ---- W1b/W2b: plain f32 -> bf16 coalesced converts (no transpose).
        int base = (blockIdx.x - SEG_WRT) * 2048 + t;
        #pragma unroll
        for (int e = 0; e < 16; ++e) {
            int idx = base + e * 128;
            if (idx < L_ * H_ * FF_) W1b[idx] = (__bf16)W1[idx];
            else W2b[idx - L_ * H_ * FF_] = (__bf16)W2[idx - L_ * H_ * FF_];
        }
    }
}

// ---------------- mega: one block per TWO rows; R27: coalesced GEMV phases.
// Evidence (R1: 2x waves + 2x uncoalesced loads -> 1.7x time; VALUBusy pinned
// 21% at both 5 and 10 waves/CU) => vector-memory TRANSACTION-throughput bound.
// wvec/ctx/FFh/FFo switched from per-lane-own-row (64 lines/wave-inst) to
// lane-consecutive reads + LDS-broadcast reduction input (1-4 lines/inst).
__global__ __launch_bounds__(256, 2) void mega_kernel(
    const float* __restrict__ chars,
    const int* __restrict__ pos_s, const int* __restrict__ pos_e,
    const int* __restrict__ lex_s, const int* __restrict__ lex_e,
    const int* __restrict__ seq_len, const int* __restrict__ lex_num,
    const float* __restrict__ Wq, const float* __restrict__ bq,
    const float* __restrict__ br,
    const float* __restrict__ u_bias, const float* __restrict__ v_bias,
    const float* __restrict__ ln1_g, const float* __restrict__ ln1_b,
    const float* __restrict__ ln2_g, const float* __restrict__ ln2_b,
    const float* __restrict__ b1, const float* __restrict__ b2,
    const __bf16* __restrict__ kb, const __bf16* __restrict__ PEWb,
    const __bf16* __restrict__ vb, const __bf16* __restrict__ WrTb,
    const __bf16* __restrict__ W1b, const __bf16* __restrict__ W2b,
    float* __restrict__ out) {

    __shared__ __align__(16) float s_x[2][H_], s_qv[2][H_];
    __shared__ __align__(16) __bf16 s_wvecb[2][16][WVS_];
    __shared__ __align__(16) __bf16 s_qub[2][16][WVS_];
    __shared__ float s_bterm[2][NH_];
    __shared__ __align__(16) float s_sc[2][NH_][WP_];
    __shared__ float s_red[2][132];
    __shared__ __align__(16) float s_hid[2][FF_];
    __shared__ float s_tmp[2][256];
    __shared__ int s_ls[W_], s_le[W_];

    int blk = blockIdx.x;
    int b = blk / CH_, c0 = blk % CH_;
    int t = threadIdx.x;
    int lane = t & 63;
    int wid = t >> 6;
    int l15 = lane & 15, quad = lane >> 4;

    if (t < H_) {
        s_x[0][t] = chars[(b * C_ + c0) * H_ + t];
        s_x[1][t] = chars[(b * C_ + c0 + CH_) * H_ + t];
    }
    for (int w = t; w < W_; w += 256) {
        s_ls[w] = lex_s[b * W_ + w];
        s_le[w] = lex_e[b * W_ + w];
    }
    for (int i = t; i < 2 * 8 * WVS_; i += 256) {
        int r = i / (8 * WVS_), rem = i % (8 * WVS_);
        s_wvecb[r][8 + rem / WVS_][rem % WVS_] = (__bf16)0.f;
    }
    for (int i = t; i < 2 * 16 * WVS_; i += 256) {
        int r = i / (16 * WVS_), rem = i % (16 * WVS_);
        s_qub[r][rem / WVS_][rem % WVS_] = (__bf16)0.f;
    }
    int ps0 = pos_s[b * C_ + c0],        pev0 = pos_e[b * C_ + c0];
    int ps1 = pos_s[b * C_ + c0 + CH_],  pev1 = pos_e[b * C_ + c0 + CH_];
    int slen = seq_len[b];
    int cvalid0 = (c0 < slen), cvalid1 = (c0 + CH_ < slen);
    int wnum = lex_num[b];
    __syncthreads();

    // layer-invariant rel A-fragment cache (built li=0, reused li=1)
    bf16x8 Ac0[5][4], Ac1[5][4];

    #pragma unroll
    for (int li = 0; li < L_; ++li) {
        // ---- q projection (coalesced f32 Wq reads; unchanged)
        {
            int half = t >> 7, h = t & 127;
            const float* WqL = Wq + li * H_ * H_;
            const float4* x40 = (const float4*)s_x[0];
            const float4* x41 = (const float4*)s_x[1];
            float4 a0 = {0,0,0,0}, a1 = {0,0,0,0};
            #pragma unroll 2
            for (int g = half * 16; g < half * 16 + 16; ++g) {
                float4 xa = x40[g], xb = x41[g];
                int j0 = 4 * g;
                float w0 = WqL[(j0 + 0) * H_ + h], w1 = WqL[(j0 + 1) * H_ + h];
                float w2 = WqL[(j0 + 2) * H_ + h], w3 = WqL[(j0 + 3) * H_ + h];
                a0.x += xa.x * w0; a0.y += xa.y * w1; a0.z += xa.z * w2; a0.w += xa.w * w3;
                a1.x += xb.x * w0; a1.y += xb.y * w1; a1.z += xb.z * w2; a1.w += xb.w * w3;
            }
            s_tmp[0][t] = (a0.x + a0.y) + (a0.z + a0.w);
            s_tmp[1][t] = (a1.x + a1.y) + (a1.z + a1.w);
        }
        __syncthreads();
        if (t < H_) {
            #pragma unroll
            for (int r = 0; r < 2; ++r) {
                float acc = s_tmp[r][t] + s_tmp[r][t + 128] + bq[li * H_ + t];
                s_qub[r][t >> 4][t] = (__bf16)(acc + u_bias[li * H_ + t]);
                s_qv[r][t] = acc + v_bias[li * H_ + t];
            }
        }
        __syncthreads();

        // ---- wvec (coalesced: WrT[k][t], lanes consecutive t) + bterm
        {
            int half = t >> 7, tt = t & 127;
            const __bf16* WrTl = WrTb + (size_t)li * H_ * H_;
            float accn[NH_];
            #pragma unroll
            for (int n = 0; n < NH_; ++n) accn[n] = 0.f;
            #pragma unroll 4
            for (int k = 0; k < PH_; ++k) {
                #pragma unroll
                for (int n = 0; n < NH_; ++n) {
                    float wv = (float)WrTl[(size_t)(n * PH_ + k) * H_ + tt];
                    accn[n] += wv * s_qv[half][n * PH_ + k];
                }
            }
            #pragma unroll
            for (int n = 0; n < NH_; ++n)
                s_wvecb[half][n][tt] = (__bf16)accn[n];
            if (t < 2 * NH_) {
                int r = t >> 3, n = t & 7;
                float a = 0.f;
                #pragma unroll
                for (int k = 0; k < PH_; ++k)
                    a += br[li * H_ + n * PH_ + k] * s_qv[r][n * PH_ + k];
                s_bterm[r][n] = a;
            }
        }
        __syncthreads();

        // ---- score via MFMA; rel A-fragments gathered only in layer 0
        const __bf16* kL = kb + (size_t)(li * B_ + b) * W_ * H_;
        {
            const __bf16* wrow0 = &s_wvecb[0][l15][0];
            const __bf16* wrow1 = &s_wvecb[1][l15][0];
            const __bf16* qrow0 = &s_qub[0][l15][0];
            const __bf16* qrow1 = &s_qub[1][l15][0];
            #pragma unroll
            for (int tc = 0; tc < 5; ++tc) {
                int tile = wid + 4 * tc;
                if (tile < NTILE_) {
                    int w0t = tile * 16;
                    int w = w0t + l15; if (w > W_ - 1) w = W_ - 1;
                    const __bf16* kr = kL + (size_t)w * H_;
                    f32x4v acc0 = {0.f,0.f,0.f,0.f}, acc1 = {0.f,0.f,0.f,0.f};
                    if (li == 0) {
                        int ls = s_ls[w], le = s_le[w];
                        int i00 = min(max(ps0 - ls + MAXLEN_, 0), PEN_ - 1);
                        int i01 = min(max(ps0 - le + MAXLEN_, 0), PEN_ - 1);
                        int i02 = min(max(pev0 - ls + MAXLEN_, 0), PEN_ - 1);
                        int i03 = min(max(pev0 - le + MAXLEN_, 0), PEN_ - 1);
                        int i10 = min(max(ps1 - ls + MAXLEN_, 0), PEN_ - 1);
                        int i11 = min(max(ps1 - le + MAXLEN_, 0), PEN_ - 1);
                        int i12 = min(max(pev1 - ls + MAXLEN_, 0), PEN_ - 1);
                        int i13 = min(max(pev1 - le + MAXLEN_, 0), PEN_ - 1);
                        const __bf16* r00 = PEWb + (size_t)(0 * PEN_ + i00) * H_;
                        const __bf16* r01 = PEWb + (size_t)(1 * PEN_ + i01) * H_;
                        const __bf16* r02 = PEWb + (size_t)(2 * PEN_ + i02) * H_;
                        const __bf16* r03 = PEWb + (size_t)(3 * PEN_ + i03) * H_;
                        const __bf16* r10 = PEWb + (size_t)(0 * PEN_ + i10) * H_;
                        const __bf16* r11 = PEWb + (size_t)(1 * PEN_ + i11) * H_;
                        const __bf16* r12 = PEWb + (size_t)(2 * PEN_ + i12) * H_;
                        const __bf16* r13 = PEWb + (size_t)(3 * PEN_ + i13) * H_;
                        #pragma unroll
                        for (int s = 0; s < 4; ++s) {
                            int h0 = s * 32 + quad * 8;
                            bf16x8 K = *(const bf16x8*)(kr + h0);
                            bf16x8 A0, A1;
                            {
                                bf16x8 t0 = *(const bf16x8*)(r00 + h0);
                                bf16x8 t1 = *(const bf16x8*)(r01 + h0);
                                bf16x8 t2 = *(const bf16x8*)(r02 + h0);
                                bf16x8 t3 = *(const bf16x8*)(r03 + h0);
                                #pragma unroll
                                for (int j = 0; j < 8; ++j)
                                    A0[j] = (__bf16)fmaxf((float)t0[j] + (float)t1[j] + (float)t2[j] + (float)t3[j], 0.f);
                            }
                            {
                                bf16x8 t0 = *(const bf16x8*)(r10 + h0);
                                bf16x8 t1 = *(const bf16x8*)(r11 + h0);
                                bf16x8 t2 = *(const bf16x8*)(r12 + h0);
                                bf16x8 t3 = *(const bf16x8*)(r13 + h0);
                                #pragma unroll
                                for (int j = 0; j < 8; ++j)
                                    A1[j] = (__bf16)fmaxf((float)t0[j] + (float)t1[j] + (float)t2[j] + (float)t3[j], 0.f);
                            }
                            Ac0[tc][s] = A0;
                            Ac1[tc][s] = A1;
                            bf16x8 Bf0 = *(const bf16x8*)(wrow0 + h0);
                            acc0 = __builtin_amdgcn_mfma_f32_16x16x32_bf16(A0, Bf0, acc0, 0, 0, 0);
                            bf16x8 Bq0 = *(const bf16x8*)(qrow0 + h0);
                            acc0 = __builtin_amdgcn_mfma_f32_16x16x32_bf16(K, Bq0, acc0, 0, 0, 0);
                            bf16x8 Bf1 = *(const bf16x8*)(wrow1 + h0);
                            acc1 = __builtin_amdgcn_mfma_f32_16x16x32_bf16(A1, Bf1, acc1, 0, 0, 0);
                            bf16x8 Bq1 = *(const bf16x8*)(qrow1 + h0);
                            acc1 = __builtin_amdgcn_mfma_f32_16x16x32_bf16(K, Bq1, acc1, 0, 0, 0);
                        }
                    } else {
                        #pragma unroll
                        for (int s = 0; s < 4; ++s) {
                            int h0 = s * 32 + quad * 8;
                            bf16x8 K = *(const bf16x8*)(kr + h0);
                            bf16x8 A0 = Ac0[tc][s];
                            bf16x8 A1 = Ac1[tc][s];
                            bf16x8 Bf0 = *(const bf16x8*)(wrow0 + h0);
                            acc0 = __builtin_amdgcn_mfma_f32_16x16x32_bf16(A0, Bf0, acc0, 0, 0, 0);
                            bf16x8 Bq0 = *(const bf16x8*)(qrow0 + h0);
                            acc0 = __builtin_amdgcn_mfma_f32_16x16x32_bf16(K, Bq0, acc0, 0, 0, 0);
                            bf16x8 Bf1 = *(const bf16x8*)(wrow1 + h0);
                            acc1 = __builtin_amdgcn_mfma_f32_16x16x32_bf16(A1, Bf1, acc1, 0, 0, 0);
                            bf16x8 Bq1 = *(const bf16x8*)(qrow1 + h0);
                            acc1 = __builtin_amdgcn_mfma_f32_16x16x32_bf16(K, Bq1, acc1, 0, 0, 0);
                        }
                    }
                    if (l15 < NH_) {
                        float bt0 = s_bterm[0][l15], bt1 = s_bterm[1][l15];
                        #pragma unroll
                        for (int r = 0; r < 4; ++r) {
                            int wr = w0t + quad * 4 + r;
                            if (wr < W_) {
                                s_sc[0][l15][wr] = acc0[r] + bt0;
                                s_sc[1][l15][wr] = acc1[r] + bt1;
                            }
                        }
                    }
                }
            }
        }
        __syncthreads();

        // ---- softmax per head, per row (unchanged)
        {
            int n = t >> 5, ln_ = t & 31;
            #pragma unroll
            for (int r = 0; r < 2; ++r) {
                int cval = r ? cvalid1 : cvalid0;
                if (cval) {
                    float m = -INFINITY;
                    for (int w = ln_; w < wnum; w += 32) m = fmaxf(m, s_sc[r][n][w]);
                    #pragma unroll
                    for (int off = 16; off > 0; off >>= 1) m = fmaxf(m, __shfl_xor(m, off, 32));
                    float sum = 0.f;
                    for (int w = ln_; w < wnum; w += 32) sum += expf(s_sc[r][n][w] - m);
                    #pragma unroll
                    for (int off = 16; off > 0; off >>= 1) sum += __shfl_xor(sum, off, 32);
                    float inv = 1.f / sum;
                    for (int w = ln_; w < WP_; w += 32)
                        s_sc[r][n][w] = (w < wnum) ? expf(s_sc[r][n][w] - m) * inv : 0.f;
                } else {
                    for (int w = ln_; w < WP_; w += 32) s_sc[r][n][w] = 0.f;
                }
            }
        }
        __syncthreads();

        // ---- ctx = att @ v (coalesced: v[w][h], lanes consecutive h; att from LDS)
        {
            int h = t & 127, half = t >> 7, n = h >> 4;
            const __bf16* vrow = vb + ((size_t)(li * B_ + b) * W_ + half * 150) * H_ + h;
            const float* att0 = s_sc[0][n] + half * 150;
            const float* att1 = s_sc[1][n] + half * 150;
            float a0 = 0.f, a1 = 0.f;
            #pragma unroll 10
            for (int w = 0; w < 150; ++w) {
                float vv = (float)vrow[(size_t)w * H_];
                a0 += att0[w] * vv;
                a1 += att1[w] * vv;
            }
            s_tmp[0][t] = a0;
            s_tmp[1][t] = a1;
        }
        __syncthreads();

        // ---- LN1
        if (t < 128) {
            s_red[0][t] = s_tmp[0][t] + s_tmp[0][t + 128] + s_x[0][t];
        } else {
            int e = t - 128;
            s_red[1][e] = s_tmp[1][e] + s_tmp[1][e + 128] + s_x[1][e];
        }
        __syncthreads();
        if (t < 128) {
            int r = t >> 6, l = t & 63;
            float a = s_red[r][l], bb = s_red[r][l + 64];
            float s = a + bb, ss = a * a + bb * bb;
            #pragma unroll
            for (int off = 32; off > 0; off >>= 1) {
                s += __shfl_down(s, off);
                ss += __shfl_down(ss, off);
            }
            if (l == 0) {
                float mean = s * (1.f / 128.f);
                float var = ss * (1.f / 128.f) - mean * mean;
                s_red[r][128] = mean;
                s_red[r][129] = rsqrtf(var + 1e-5f);
            }
        }
        __syncthreads();
        if (t < H_) {
            float g1 = ln1_g[li * H_ + t], b1v = ln1_b[li * H_ + t];
            #pragma unroll
            for (int r = 0; r < 2; ++r)
                s_x[r][t] = (s_red[r][t] - s_red[r][128]) * s_red[r][129] * g1 + b1v;
        }
        __syncthreads();

        // ---- FF hidden (coalesced: W1b[j][u] natural, bf16x2 per lane; x from LDS)
        {
            const __bf16* W1l = W1b + (size_t)li * H_ * FF_;
            int u0 = t * 2;
            float a00 = 0.f, a01 = 0.f, a10 = 0.f, a11 = 0.f;
            #pragma unroll 8
            for (int j = 0; j < H_; ++j) {
                bf16x2 wp = *(const bf16x2*)(W1l + (size_t)j * FF_ + u0);
                float wa = (float)wp[0], wb = (float)wp[1];
                float xa = s_x[0][j], xb = s_x[1][j];   // LDS broadcast
                a00 += xa * wa; a01 += xa * wb;
                a10 += xb * wa; a11 += xb * wb;
            }
            float bb0 = b1[li * FF_ + u0], bb1 = b1[li * FF_ + u0 + 1];
            s_hid[0][u0]     = fmaxf(a00 + bb0, 0.f);
            s_hid[0][u0 + 1] = fmaxf(a01 + bb1, 0.f);
            s_hid[1][u0]     = fmaxf(a10 + bb0, 0.f);
            s_hid[1][u0 + 1] = fmaxf(a11 + bb1, 0.f);
        }
        __syncthreads();

        // ---- FF out (coalesced: W2b[u][h] natural, lanes consecutive h; hid from LDS)
        {
            int h = t & 127, half = t >> 7;
            const __bf16* W2l = W2b + ((size_t)li * FF_ + half * 256) * H_ + h;
            const float* h0 = s_hid[0] + half * 256;
            const float* h1 = s_hid[1] + half * 256;
            float a0 = 0.f, a1 = 0.f;
            #pragma unroll 8
            for (int u = 0; u < 256; ++u) {
                float wv = (float)W2l[(size_t)u * H_];
                a0 += h0[u] * wv;
                a1 += h1[u] * wv;
            }
            s_tmp[0][t] = a0;
            s_tmp[1][t] = a1;
        }
        __syncthreads();

        // ---- LN2
        if (t < 128) {
            s_red[0][t] = s_tmp[0][t] + s_tmp[0][t + 128] + b2[li * H_ + t] + s_x[0][t];
        } else {
            int e = t - 128;
            s_red[1][e] = s_tmp[1][e] + s_tmp[1][e + 128] + b2[li * H_ + e] + s_x[1][e];
        }
        __syncthreads();
        if (t < 128) {
            int r = t >> 6, l = t & 63;
            float a = s_red[r][l], bb = s_red[r][l + 64];
            float s = a + bb, ss = a * a + bb * bb;
            #pragma unroll
            for (int off = 32; off > 0; off >>= 1) {
                s += __shfl_down(s, off);
                ss += __shfl_down(ss, off);
            }
            if (l == 0) {
                float mean = s * (1.f / 128.f);
                float var = ss * (1.f / 128.f) - mean * mean;
                s_red[r][128] = mean;
                s_red[r][129] = rsqrtf(var + 1e-5f);
            }
        }
        __syncthreads();
        if (t < H_) {
            float g2 = ln2_g[li * H_ + t], b2v = ln2_b[li * H_ + t];
            #pragma unroll
            for (int r = 0; r < 2; ++r)
                s_x[r][t] = (s_red[r][t] - s_red[r][128]) * s_red[r][129] * g2 + b2v;
        }
        __syncthreads();
    }

    if (t < H_) {
        out[(b * C_ + c0) * H_ + t] = s_x[0][t];
        out[(b * C_ + c0 + CH_) * H_ + t] = s_x[1][t];
    }
}

extern "C" void kernel_launch(void* const* d_in, const int* in_sizes, int n_in,
                              void* d_out, int out_size, void* d_ws, size_t ws_size,
                              hipStream_t stream) {
    const float* chars  = (const float*)d_in[0];
    const float* words  = (const float*)d_in[1];
    const int* pos_s   = (const int*)d_in[2];
    const int* pos_e   = (const int*)d_in[3];
    const int* lex_s   = (const int*)d_in[4];
    const int* lex_e   = (const int*)d_in[5];
    const int* seq_len = (const int*)d_in[6];
    const int* lex_num = (const int*)d_in[7];
    const float* Wf  = (const float*)d_in[8];
    const float* bfv = (const float*)d_in[9];
    const float* Wq  = (const float*)d_in[10];
    const float* bq  = (const float*)d_in[11];
    const float* Wk  = (const float*)d_in[12];
    const float* bk  = (const float*)d_in[13];
    const float* Wv  = (const float*)d_in[14];
    const float* bv  = (const float*)d_in[15];
    const float* Wr  = (const float*)d_in[16];
    const float* br  = (const float*)d_in[17];
    const float* u_bias = (const float*)d_in[18];
    const float* v_bias = (const float*)d_in[19];
    const float* ln1_g  = (const float*)d_in[20];
    const float* ln1_b  = (const float*)d_in[21];
    const float* ln2_g  = (const float*)d_in[22];
    const float* ln2_b  = (const float*)d_in[23];
    const float* W1  = (const float*)d_in[24];
    const float* b1  = (const float*)d_in[25];
    const float* W2  = (const float*)d_in[26];
    const float* b2  = (const float*)d_in[27];

    __bf16* kb   = (__bf16*)d_ws;                      // 307200
    __bf16* PEWb = kb + (size_t)L_ * B_ * W_ * H_;     // 262144
    __bf16* vb   = PEWb + 4 * PEN_ * H_;               // 307200
    __bf16* W1b  = vb + (size_t)L_ * B_ * W_ * H_;     // 131072
    __bf16* W2b  = W1b + (size_t)L_ * H_ * FF_;        // 131072
    __bf16* WrT  = W2b + (size_t)L_ * FF_ * H_;        // 32768

    prep_kernel<<<dim3(PREP_BLOCKS), dim3(128), 0, stream>>>(
        Wf, bfv, words, Wk, bk, Wv, bv, Wr, W1, W2,
        kb, PEWb, vb, WrT, W1b, W2b);

    mega_kernel<<<dim3(B_ * CH_), dim3(256), 0, stream>>>(
        chars, pos_s, pos_e, lex_s, lex_e, seq_len, lex_num,
        Wq, bq, br, u_bias, v_bias,
        ln1_g, ln1_b, ln2_g, ln2_b, b1, b2,
        kb, PEWb, vb, WrT, W1b, W2b, (float*)d_out);
}